// Round 5
// baseline (437.044 us; speedup 1.0000x reference)
//
#include <hip/hip_runtime.h>
#include <hip/hip_cooperative_groups.h>
#include <math.h>

namespace cg = cooperative_groups;

#define LN_EPS 1e-5f

typedef __attribute__((ext_vector_type(8))) short bf16x8;
typedef __attribute__((ext_vector_type(4))) float f32x4;
typedef unsigned short ushort_t;
typedef unsigned int uint_t;

__device__ __forceinline__ ushort_t f2bf(float f) {
    uint_t u = __float_as_uint(f);
    u += 0x7FFF + ((u >> 16) & 1);          // RNE
    return (ushort_t)(u >> 16);
}

__device__ __forceinline__ bf16x8 cvt8(float4 a, float4 b) {
    bf16x8 r;
    r[0] = (short)f2bf(a.x); r[1] = (short)f2bf(a.y);
    r[2] = (short)f2bf(a.z); r[3] = (short)f2bf(a.w);
    r[4] = (short)f2bf(b.x); r[5] = (short)f2bf(b.y);
    r[6] = (short)f2bf(b.z); r[7] = (short)f2bf(b.w);
    return r;
}

// ---------------------------------------------------------------------------
// Single cooperative kernel, 5 phases separated by grid.sync():
//  0: activations fp32->bf16, weight transpose-convert, stats zero
//  1: proj GEMMs (bf16 A) + bias + relu + per-row LN stats (atomics)
//  2: h GEMMs with LayerNorm fused on the A-load (stats -> mu/rstd)
//  3: pair scores + sigmoid -> out[0]
//  4: per-batch softmax + LN-folded aggregation -> out[1]
// All phases are grid-stride, correct for any grid size.
// ---------------------------------------------------------------------------
__global__ void mega_kernel(
    const float* __restrict__ text, const float* __restrict__ image,
    const float* __restrict__ W_text, const float* __restrict__ b_text,
    const float* __restrict__ g_text, const float* __restrict__ beta_text,
    const float* __restrict__ W_img, const float* __restrict__ b_img,
    const float* __restrict__ g_img, const float* __restrict__ beta_img,
    const float* __restrict__ W1, const float* __restrict__ b1,
    const float* __restrict__ W2, const float* __restrict__ b2,
    float* __restrict__ out_scores, float* __restrict__ out_agg,
    char* __restrict__ ws)
{
    __shared__ __align__(16) float red[4][64][64];   // 64 KB, reused per phase

    ushort_t* text_bf  = (ushort_t*)(ws);
    ushort_t* image_bf = (ushort_t*)(ws + 3145728);
    float*    ta       = (float*)(ws + 7864320);     // raw relu'd proj, fp32
    float*    ia       = (float*)(ws + 12058624);
    float*    ht       = (float*)(ws + 14417920);
    float*    hi       = (float*)(ws + 18612224);
    ushort_t* Wt_t     = (ushort_t*)(ws + 20971520); // [512][768]
    ushort_t* Wi_t     = (ushort_t*)(ws + 21757952); // [512][2048]
    ushort_t* W1t_t    = (ushort_t*)(ws + 23855104); // [512][512]
    ushort_t* W1i_t    = (ushort_t*)(ws + 24379392); // [512][512]
    float*    stats    = (float*)(ws + 24903680);    // 3200 x {sum,sumsq}

    cg::grid_group gg = cg::this_grid();
    const int tid  = threadIdx.x;
    const int wave = tid >> 6;
    const int lane = tid & 63;
    const int q    = lane >> 4;
    const int mj   = lane & 15;

    // ------------------------------------------------------------ phase 0
    for (int u = blockIdx.x; u < 5761; u += gridDim.x) {
        if (u < 3840) {
            const int i4 = u * 1024 + tid * 4;
            const float* src; ushort_t* dst; int off;
            if (i4 < 1572864) { src = text;  dst = text_bf;  off = i4; }
            else              { src = image; dst = image_bf; off = i4 - 1572864; }
            float4 v = *(const float4*)(src + off);
            ushort4 o;
            o.x = f2bf(v.x); o.y = f2bf(v.y); o.z = f2bf(v.z); o.w = f2bf(v.w);
            *(ushort4*)(dst + off) = o;
        } else if (u < 5760) {
            float (*t33)[33] = (float(*)[33])&red[0][0][0];
            int local = u - 3840;
            const float* src; ushort_t* dst; int K;
            if      (local < 384)  { src = W_text;         dst = Wt_t;  K = 768;  }
            else if (local < 1408) { src = W_img;          dst = Wi_t;  K = 2048; local -= 384; }
            else if (local < 1664) { src = W1;             dst = W1t_t; K = 512;  local -= 1408; }
            else                   { src = W1 + 512 * 512; dst = W1i_t; K = 512;  local -= 1664; }
            const int ntk = K / 32;
            const int k0 = (local % ntk) * 32;
            const int n0 = (local / ntk) * 32;
            const int x = tid % 32, y = tid / 32;
            __syncthreads();    // prior iteration's readers done
            #pragma unroll
            for (int j = 0; j < 4; ++j)
                t33[y + 8 * j][x] = src[(size_t)(k0 + y + 8 * j) * 512 + n0 + x];
            __syncthreads();
            #pragma unroll
            for (int j = 0; j < 4; ++j)
                dst[(size_t)(n0 + y + 8 * j) * K + k0 + x] = f2bf(t33[x][y + 8 * j]);
        } else {
            for (int i = tid; i < 6400; i += 256) stats[i] = 0.f;
        }
    }

    gg.sync();
    // ------------------------------------------------------------ phase 1
    for (int u = blockIdx.x; u < 400; u += gridDim.x) {
        const ushort_t* A; const ushort_t* Bt; const float* bias; float* C;
        int K, srow, yy, xx;
        if (u < 256) {
            yy = u >> 3; xx = u & 7;
            A = text_bf; Bt = Wt_t; bias = b_text; C = ta; K = 768; srow = yy * 64;
        } else {
            int v = u - 256; yy = v >> 3; xx = v & 7;
            A = image_bf; Bt = Wi_t; bias = b_img; C = ia; K = 2048; srow = 2048 + yy * 64;
        }
        const int brow = yy * 64, bcol = xx * 64;
        const ushort_t* Ab = A  + (size_t)(brow + mj) * K + q * 8;
        const ushort_t* Bb = Bt + (size_t)(bcol + mj) * K + q * 8;
        const int kw0 = wave * (K >> 2);
        const int ksteps = K >> 7;

        f32x4 acc[4][4] = {};
        #pragma unroll 2
        for (int s = 0; s < ksteps; ++s) {
            const int k = kw0 + s * 32;
            bf16x8 af[4], bfr[4];
            #pragma unroll
            for (int i = 0; i < 4; ++i) {
                af[i]  = *(const bf16x8*)(Ab + (size_t)i * 16 * K + k);
                bfr[i] = *(const bf16x8*)(Bb + (size_t)i * 16 * K + k);
            }
            #pragma unroll
            for (int mi = 0; mi < 4; ++mi)
                #pragma unroll
                for (int ni = 0; ni < 4; ++ni)
                    acc[mi][ni] = __builtin_amdgcn_mfma_f32_16x16x32_bf16(
                        af[mi], bfr[ni], acc[mi][ni], 0, 0, 0);
        }
        #pragma unroll
        for (int mi = 0; mi < 4; ++mi)
            #pragma unroll
            for (int ni = 0; ni < 4; ++ni)
                #pragma unroll
                for (int r = 0; r < 4; ++r)
                    red[wave][mi * 16 + q * 4 + r][ni * 16 + mj] = acc[mi][ni][r];
        __syncthreads();
        #pragma unroll
        for (int g4 = 0; g4 < 4; ++g4) {
            const int idx = g4 * 1024 + tid * 4;
            const int row = idx >> 6, col = idx & 63;
            float4 v0 = *(float4*)&red[0][row][col];
            float4 v1 = *(float4*)&red[1][row][col];
            float4 v2 = *(float4*)&red[2][row][col];
            float4 v3 = *(float4*)&red[3][row][col];
            float4 bv = *(const float4*)&bias[bcol + col];
            float4 o;
            o.x = fmaxf((v0.x + v1.x) + (v2.x + v3.x) + bv.x, 0.f);
            o.y = fmaxf((v0.y + v1.y) + (v2.y + v3.y) + bv.y, 0.f);
            o.z = fmaxf((v0.z + v1.z) + (v2.z + v3.z) + bv.z, 0.f);
            o.w = fmaxf((v0.w + v1.w) + (v2.w + v3.w) + bv.w, 0.f);
            *(float4*)&C[(size_t)(brow + row) * 512 + bcol + col] = o;
            float s  = (o.x + o.y) + (o.z + o.w);
            float ss = (o.x * o.x + o.y * o.y) + (o.z * o.z + o.w * o.w);
            #pragma unroll
            for (int m = 1; m < 16; m <<= 1) {
                s  += __shfl_xor(s, m);
                ss += __shfl_xor(ss, m);
            }
            if ((tid & 15) == 0) {
                atomicAdd(&stats[(size_t)(srow + row) * 2], s);
                atomicAdd(&stats[(size_t)(srow + row) * 2 + 1], ss);
            }
        }
        __syncthreads();
    }

    gg.sync();
    // ------------------------------------------------------------ phase 2
    for (int u = blockIdx.x; u < 400; u += gridDim.x) {
        const float* A; const ushort_t* Bt; const float* bias; float* C;
        const float* g; const float* be; int soff, yy, xx;
        if (u < 256) {
            yy = u >> 3; xx = u & 7;
            A = ta; Bt = W1t_t; bias = nullptr; C = ht;
            g = g_text; be = beta_text; soff = 0;
        } else {
            int v = u - 256; yy = v >> 3; xx = v & 7;
            A = ia; Bt = W1i_t; bias = b1; C = hi;
            g = g_img; be = beta_img; soff = 2048;
        }
        const int brow = yy * 64, bcol = xx * 64;

        float mu[4], rstd[4];
        #pragma unroll
        for (int i = 0; i < 4; ++i) {
            const int row = soff + brow + i * 16 + mj;
            float2 st = *(const float2*)&stats[(size_t)row * 2];
            float m   = st.x * (1.f / 512.f);
            float var = st.y * (1.f / 512.f) - m * m;
            mu[i] = m; rstd[i] = rsqrtf(var + LN_EPS);
        }

        const float*    Ab = A  + (size_t)(brow + mj) * 512 + q * 8;
        const ushort_t* Bb = Bt + (size_t)(bcol + mj) * 512 + q * 8;
        const int kw0 = wave * 128;

        f32x4 acc[4][4] = {};
        #pragma unroll 2
        for (int s = 0; s < 4; ++s) {
            const int k = kw0 + s * 32;
            float4 gv0 = *(const float4*)&g[k + q * 8];
            float4 gv1 = *(const float4*)&g[k + q * 8 + 4];
            float4 bv0 = *(const float4*)&be[k + q * 8];
            float4 bv1 = *(const float4*)&be[k + q * 8 + 4];
            bf16x8 af[4], bfr[4];
            #pragma unroll
            for (int i = 0; i < 4; ++i) {
                const float* pA = Ab + (size_t)i * 16 * 512 + k;
                float4 x0 = *(const float4*)pA;
                float4 x1 = *(const float4*)(pA + 4);
                float4 t0, t1;
                t0.x = fmaf((x0.x - mu[i]) * rstd[i], gv0.x, bv0.x);
                t0.y = fmaf((x0.y - mu[i]) * rstd[i], gv0.y, bv0.y);
                t0.z = fmaf((x0.z - mu[i]) * rstd[i], gv0.z, bv0.z);
                t0.w = fmaf((x0.w - mu[i]) * rstd[i], gv0.w, bv0.w);
                t1.x = fmaf((x1.x - mu[i]) * rstd[i], gv1.x, bv1.x);
                t1.y = fmaf((x1.y - mu[i]) * rstd[i], gv1.y, bv1.y);
                t1.z = fmaf((x1.z - mu[i]) * rstd[i], gv1.z, bv1.z);
                t1.w = fmaf((x1.w - mu[i]) * rstd[i], gv1.w, bv1.w);
                af[i]  = cvt8(t0, t1);
                bfr[i] = *(const bf16x8*)(Bb + (size_t)i * 16 * 512 + k);
            }
            #pragma unroll
            for (int mi = 0; mi < 4; ++mi)
                #pragma unroll
                for (int ni = 0; ni < 4; ++ni)
                    acc[mi][ni] = __builtin_amdgcn_mfma_f32_16x16x32_bf16(
                        af[mi], bfr[ni], acc[mi][ni], 0, 0, 0);
        }
        #pragma unroll
        for (int mi = 0; mi < 4; ++mi)
            #pragma unroll
            for (int ni = 0; ni < 4; ++ni)
                #pragma unroll
                for (int r = 0; r < 4; ++r)
                    red[wave][mi * 16 + q * 4 + r][ni * 16 + mj] = acc[mi][ni][r];
        __syncthreads();
        #pragma unroll
        for (int g4 = 0; g4 < 4; ++g4) {
            const int idx = g4 * 1024 + tid * 4;
            const int row = idx >> 6, col = idx & 63;
            float4 v0 = *(float4*)&red[0][row][col];
            float4 v1 = *(float4*)&red[1][row][col];
            float4 v2 = *(float4*)&red[2][row][col];
            float4 v3 = *(float4*)&red[3][row][col];
            float4 o;
            o.x = (v0.x + v1.x) + (v2.x + v3.x);
            o.y = (v0.y + v1.y) + (v2.y + v3.y);
            o.z = (v0.z + v1.z) + (v2.z + v3.z);
            o.w = (v0.w + v1.w) + (v2.w + v3.w);
            if (bias) {
                float4 bv = *(const float4*)&bias[bcol + col];
                o.x += bv.x; o.y += bv.y; o.z += bv.z; o.w += bv.w;
            }
            *(float4*)&C[(size_t)(brow + row) * 512 + bcol + col] = o;
        }
        __syncthreads();
    }

    gg.sync();
    // ------------------------------------------------------------ phase 3
    for (int u = blockIdx.x; u < 512; u += gridDim.x) {
        const int b  = u >> 4;
        const int e0 = (u & 15) * 4;
        float htv[4][8], w2v[8];
        #pragma unroll
        for (int e = 0; e < 4; ++e) {
            const float* htp = ht + (size_t)(b * 64 + e0 + e) * 512;
            #pragma unroll
            for (int j = 0; j < 8; ++j) htv[e][j] = htp[lane + 64 * j];
        }
        #pragma unroll
        for (int j = 0; j < 8; ++j) w2v[j] = W2[lane + 64 * j];
        const float bb = b2[0];
        const float* hib = hi + (size_t)b * 36 * 512;

        for (int r = wave; r < 36; r += 4) {
            const float* hir = hib + (size_t)r * 512;
            float hv[8];
            #pragma unroll
            for (int j = 0; j < 8; ++j) hv[j] = hir[lane + 64 * j];
            float a0 = 0.f, a1 = 0.f, a2 = 0.f, a3 = 0.f;
            #pragma unroll
            for (int j = 0; j < 8; ++j) {
                a0 = fmaf(fmaxf(htv[0][j] + hv[j], 0.f), w2v[j], a0);
                a1 = fmaf(fmaxf(htv[1][j] + hv[j], 0.f), w2v[j], a1);
                a2 = fmaf(fmaxf(htv[2][j] + hv[j], 0.f), w2v[j], a2);
                a3 = fmaf(fmaxf(htv[3][j] + hv[j], 0.f), w2v[j], a3);
            }
            #pragma unroll
            for (int off = 32; off; off >>= 1) {
                a0 += __shfl_down(a0, off);
                a1 += __shfl_down(a1, off);
                a2 += __shfl_down(a2, off);
                a3 += __shfl_down(a3, off);
            }
            if (lane == 0) {
                float* sp = out_scores + (size_t)(b * 64 + e0) * 36 + r;
                sp[0]   = 1.f / (1.f + expf(-(a0 + bb)));
                sp[36]  = 1.f / (1.f + expf(-(a1 + bb)));
                sp[72]  = 1.f / (1.f + expf(-(a2 + bb)));
                sp[108] = 1.f / (1.f + expf(-(a3 + bb)));
            }
        }
    }

    gg.sync();
    // ------------------------------------------------------------ phase 4
    for (int u = blockIdx.x; u < 256; u += gridDim.x) {
        const int b  = u >> 3;
        const int d0 = (u & 7) * 64;
        const float* sc = out_scores + (size_t)b * 2304;
        float (*part)[36] = (float(*)[36])&red[0][0][0];
        float* wsr = &red[1][0][0];
        float* tmp = &red[2][0][0];
        float* msc = &red[3][0][0];

        const int e4 = tid >> 6;
        const int r  = tid & 63;
        __syncthreads();
        if (r < 36) {
            float p = 0.f;
            #pragma unroll
            for (int e = 0; e < 16; ++e) p += expf(sc[(e * 4 + e4) * 36 + r]);
            part[e4][r] = p;
        }
        __syncthreads();
        if (tid < 36) wsr[tid] = part[0][tid] + part[1][tid] + part[2][tid] + part[3][tid];
        __syncthreads();
        if (tid < 64) {
            float v = (tid < 36) ? wsr[tid] : 0.f;
            #pragma unroll
            for (int off = 32; off; off >>= 1) v += __shfl_down(v, off);
            if (tid == 0) msc[0] = 1.f / (v * 64.f);
        }
        __syncthreads();
        if (tid < 36) {
            const int row = b * 36 + tid;
            float2 st = *(const float2*)&stats[(size_t)(2048 + row) * 2];
            float m   = st.x * (1.f / 512.f);
            float var = st.y * (1.f / 512.f) - m * m;
            float rs  = rsqrtf(var + LN_EPS);
            float W   = wsr[tid] * msc[0];
            wsr[tid]  = W * rs;
            tmp[tid]  = W * rs * m;
        }
        __syncthreads();
        if (tid < 64) {
            float v = (tid < 36) ? tmp[tid] : 0.f;
            #pragma unroll
            for (int off = 32; off; off >>= 1) v += __shfl_down(v, off);
            if (tid == 0) msc[1] = v;
        }
        __syncthreads();
        if (tid < 64) {
            const int d = d0 + tid;
            const float c1 = msc[1];
            const float* ib = ia + (size_t)b * 36 * 512;
            float acc = 0.f;
            #pragma unroll
            for (int rr = 0; rr < 36; ++rr)
                acc = fmaf(wsr[rr], ib[rr * 512 + d], acc);
            out_agg[(size_t)b * 512 + d] = g_img[d] * (acc - c1) + beta_img[d] * (1.f / 64.f);
        }
        __syncthreads();
    }
}

// ---------------------------------------------------------------------------
extern "C" void kernel_launch(void* const* d_in, const int* in_sizes, int n_in,
                              void* d_out, int out_size, void* d_ws, size_t ws_size,
                              hipStream_t stream)
{
    const float* text      = (const float*)d_in[0];
    const float* image     = (const float*)d_in[1];
    const float* W_text    = (const float*)d_in[2];
    const float* b_text    = (const float*)d_in[3];
    const float* g_text    = (const float*)d_in[4];
    const float* beta_text = (const float*)d_in[5];
    const float* W_img     = (const float*)d_in[6];
    const float* b_img     = (const float*)d_in[7];
    const float* g_img     = (const float*)d_in[8];
    const float* beta_img  = (const float*)d_in[9];
    const float* W1        = (const float*)d_in[10];
    const float* b1        = (const float*)d_in[11];
    const float* W2        = (const float*)d_in[12];
    const float* b2        = (const float*)d_in[13];

    float* out_scores = (float*)d_out;            // 32*64*36
    float* out_agg    = (float*)d_out + 73728;    // 32*512
    char*  wsc        = (char*)d_ws;

    int maxPerCU = 0;
    hipError_t err = hipOccupancyMaxActiveBlocksPerMultiprocessor(
        &maxPerCU, mega_kernel, 256, 0);
    int nblk = 512;
    if (err == hipSuccess && maxPerCU > 0) {
        int cap = maxPerCU * 256;       // 256 CUs on MI355X
        if (cap < nblk) nblk = cap;
    }

    void* args[17] = {
        (void*)&text, (void*)&image,
        (void*)&W_text, (void*)&b_text, (void*)&g_text, (void*)&beta_text,
        (void*)&W_img, (void*)&b_img, (void*)&g_img, (void*)&beta_img,
        (void*)&W1, (void*)&b1, (void*)&W2, (void*)&b2,
        (void*)&out_scores, (void*)&out_agg, (void*)&wsc
    };
    hipLaunchCooperativeKernel((void*)mega_kernel, dim3(nblk), dim3(256),
                               args, 0, stream);
}

// Round 6
// 190.759 us; speedup vs baseline: 2.2911x; 2.2911x over previous
//
#include <hip/hip_runtime.h>
#include <math.h>

#define LN_EPS 1e-5f

typedef __attribute__((ext_vector_type(8))) short bf16x8;
typedef __attribute__((ext_vector_type(4))) float f32x4;
typedef unsigned short ushort_t;
typedef unsigned int uint_t;

__device__ __forceinline__ ushort_t f2bf(float f) {
    uint_t u = __float_as_uint(f);
    u += 0x7FFF + ((u >> 16) & 1);          // RNE
    return (ushort_t)(u >> 16);
}

__device__ __forceinline__ bf16x8 cvt8(float4 a, float4 b) {
    bf16x8 r;
    r[0] = (short)f2bf(a.x); r[1] = (short)f2bf(a.y);
    r[2] = (short)f2bf(a.z); r[3] = (short)f2bf(a.w);
    r[4] = (short)f2bf(b.x); r[5] = (short)f2bf(b.y);
    r[6] = (short)f2bf(b.z); r[7] = (short)f2bf(b.w);
    return r;
}

// ---------------------------------------------------------------------------
// Prep: [0,3840) convert activations fp32->bf16; [3840,5760) transpose-convert
// weights [K][512]f32 -> [512][K]bf16; block 5760 zeroes stats + counters.
// ---------------------------------------------------------------------------
__global__ __launch_bounds__(256) void prep_kernel(
    const float* __restrict__ text, const float* __restrict__ image,
    ushort_t* __restrict__ text_bf, ushort_t* __restrict__ image_bf,
    const float* __restrict__ W_text, const float* __restrict__ W_img,
    const float* __restrict__ W1,
    ushort_t* __restrict__ Wt_t, ushort_t* __restrict__ Wi_t,
    ushort_t* __restrict__ W1t_t, ushort_t* __restrict__ W1i_t,
    float* __restrict__ stats, int* __restrict__ counters)
{
    __shared__ float t[32][33];
    const int bid = blockIdx.x;
    if (bid < 3840) {
        const int i4 = (bid * 256 + threadIdx.x) * 4;
        const float* src; ushort_t* dst; int off;
        if (i4 < 1572864) { src = text;  dst = text_bf;  off = i4; }
        else              { src = image; dst = image_bf; off = i4 - 1572864; }
        float4 v = *(const float4*)(src + off);
        ushort4 o;
        o.x = f2bf(v.x); o.y = f2bf(v.y); o.z = f2bf(v.z); o.w = f2bf(v.w);
        *(ushort4*)(dst + off) = o;
        return;
    }
    if (bid >= 5760) {
        for (int i = threadIdx.x; i < 6400; i += 256) stats[i] = 0.f;
        if (threadIdx.x < 32) counters[threadIdx.x] = 0;
        return;
    }
    int local = bid - 3840;
    const float* src; ushort_t* dst; int K;
    if      (local < 384)  { src = W_text;         dst = Wt_t;  K = 768;  }
    else if (local < 1408) { src = W_img;          dst = Wi_t;  K = 2048; local -= 384; }
    else if (local < 1664) { src = W1;             dst = W1t_t; K = 512;  local -= 1408; }
    else                   { src = W1 + 512 * 512; dst = W1i_t; K = 512;  local -= 1664; }
    const int ntk = K / 32;
    const int k0 = (local % ntk) * 32;
    const int n0 = (local / ntk) * 32;
    const int x = threadIdx.x % 32, y = threadIdx.x / 32;
    #pragma unroll
    for (int j = 0; j < 4; ++j)
        t[y + 8 * j][x] = src[(size_t)(k0 + y + 8 * j) * 512 + n0 + x];
    __syncthreads();
    #pragma unroll
    for (int j = 0; j < 4; ++j)
        dst[(size_t)(n0 + y + 8 * j) * K + k0 + x] = f2bf(t[x][y + 8 * j]);
}

// ---------------------------------------------------------------------------
// Projection GEMM (bf16 A + bf16 Bt, both K-contiguous): barrier-free
// split-K over 4 waves, 64x64 tile, relu+bias epilogue + per-row LN stats.
// Two problems per launch (y < ysplit -> text).
// ---------------------------------------------------------------------------
__global__ __launch_bounds__(256) void proj_kernel(
    const ushort_t* __restrict__ A0, const ushort_t* __restrict__ B0,
    const float* __restrict__ bias0, float* __restrict__ C0, int K0,
    const ushort_t* __restrict__ A1, const ushort_t* __restrict__ B1,
    const float* __restrict__ bias1, float* __restrict__ C1, int K1,
    float* __restrict__ stats, int ysplit)
{
    __shared__ __align__(16) float red[4][64][64];    // 64 KB

    const ushort_t* A; const ushort_t* Bt; const float* bias; float* C; int K, srow;
    int yy = blockIdx.y;
    if (yy < ysplit) { A = A0; Bt = B0; bias = bias0; C = C0; K = K0; srow = yy * 64; }
    else { A = A1; Bt = B1; bias = bias1; C = C1; K = K1; yy -= ysplit; srow = 2048 + yy * 64; }

    const int tid  = threadIdx.x;
    const int wave = tid >> 6;
    const int lane = tid & 63;
    const int q    = lane >> 4;
    const int mj   = lane & 15;
    const int brow = yy * 64;
    const int bcol = blockIdx.x * 64;

    const ushort_t* Ab = A  + (size_t)(brow + mj) * K + q * 8;
    const ushort_t* Bb = Bt + (size_t)(bcol + mj) * K + q * 8;
    const int kw0    = wave * (K >> 2);
    const int ksteps = K >> 7;

    f32x4 acc[4][4] = {};

    #pragma unroll 2
    for (int s = 0; s < ksteps; ++s) {
        const int k = kw0 + s * 32;
        bf16x8 af[4], bfr[4];
        #pragma unroll
        for (int i = 0; i < 4; ++i) {
            af[i]  = *(const bf16x8*)(Ab + (size_t)i * 16 * K + k);
            bfr[i] = *(const bf16x8*)(Bb + (size_t)i * 16 * K + k);
        }
        #pragma unroll
        for (int mi = 0; mi < 4; ++mi)
            #pragma unroll
            for (int ni = 0; ni < 4; ++ni)
                acc[mi][ni] = __builtin_amdgcn_mfma_f32_16x16x32_bf16(
                    af[mi], bfr[ni], acc[mi][ni], 0, 0, 0);
    }

    #pragma unroll
    for (int mi = 0; mi < 4; ++mi)
        #pragma unroll
        for (int ni = 0; ni < 4; ++ni)
            #pragma unroll
            for (int r = 0; r < 4; ++r)
                red[wave][mi * 16 + q * 4 + r][ni * 16 + mj] = acc[mi][ni][r];
    __syncthreads();

    #pragma unroll
    for (int g4 = 0; g4 < 4; ++g4) {
        const int idx = g4 * 1024 + tid * 4;
        const int row = idx >> 6, col = idx & 63;
        float4 v0 = *(float4*)&red[0][row][col];
        float4 v1 = *(float4*)&red[1][row][col];
        float4 v2 = *(float4*)&red[2][row][col];
        float4 v3 = *(float4*)&red[3][row][col];
        float4 bv = *(const float4*)&bias[bcol + col];
        float4 o;
        o.x = fmaxf((v0.x + v1.x) + (v2.x + v3.x) + bv.x, 0.f);
        o.y = fmaxf((v0.y + v1.y) + (v2.y + v3.y) + bv.y, 0.f);
        o.z = fmaxf((v0.z + v1.z) + (v2.z + v3.z) + bv.z, 0.f);
        o.w = fmaxf((v0.w + v1.w) + (v2.w + v3.w) + bv.w, 0.f);
        *(float4*)&C[(size_t)(brow + row) * 512 + bcol + col] = o;
        float s  = (o.x + o.y) + (o.z + o.w);
        float ss = (o.x * o.x + o.y * o.y) + (o.z * o.z + o.w * o.w);
        #pragma unroll
        for (int m = 1; m < 16; m <<= 1) {
            s  += __shfl_xor(s, m);
            ss += __shfl_xor(ss, m);
        }
        if ((tid & 15) == 0) {
            atomicAdd(&stats[(size_t)(srow + row) * 2], s);
            atomicAdd(&stats[(size_t)(srow + row) * 2 + 1], ss);
        }
    }
}

// ---------------------------------------------------------------------------
// h GEMM with LayerNorm fused on the A-load (fp32 A + stats -> bf16 frags).
// ---------------------------------------------------------------------------
__global__ __launch_bounds__(256) void h_kernel(
    const float* __restrict__ A0, const ushort_t* __restrict__ B0,
    const float* __restrict__ bias0, float* __restrict__ C0,
    const float* __restrict__ g0, const float* __restrict__ be0, int soff0,
    const float* __restrict__ A1, const ushort_t* __restrict__ B1,
    const float* __restrict__ bias1, float* __restrict__ C1,
    const float* __restrict__ g1, const float* __restrict__ be1, int soff1,
    const float* __restrict__ stats, int ysplit)
{
    __shared__ __align__(16) float red[4][64][64];

    const float* A; const ushort_t* Bt; const float* bias; float* C;
    const float* g; const float* be; int soff;
    int yy = blockIdx.y;
    if (yy < ysplit) { A = A0; Bt = B0; bias = bias0; C = C0; g = g0; be = be0; soff = soff0; }
    else { A = A1; Bt = B1; bias = bias1; C = C1; g = g1; be = be1; soff = soff1; yy -= ysplit; }

    const int tid  = threadIdx.x;
    const int wave = tid >> 6;
    const int lane = tid & 63;
    const int q    = lane >> 4;
    const int mj   = lane & 15;
    const int brow = yy * 64;
    const int bcol = blockIdx.x * 64;

    float mu[4], rstd[4];
    #pragma unroll
    for (int i = 0; i < 4; ++i) {
        const int row = soff + brow + i * 16 + mj;
        float2 st = *(const float2*)&stats[(size_t)row * 2];
        float m   = st.x * (1.f / 512.f);
        float var = st.y * (1.f / 512.f) - m * m;
        mu[i] = m; rstd[i] = rsqrtf(var + LN_EPS);
    }

    const float*    Ab = A  + (size_t)(brow + mj) * 512 + q * 8;
    const ushort_t* Bb = Bt + (size_t)(bcol + mj) * 512 + q * 8;
    const int kw0 = wave * 128;

    f32x4 acc[4][4] = {};

    #pragma unroll 2
    for (int s = 0; s < 4; ++s) {
        const int k = kw0 + s * 32;
        float4 gv0 = *(const float4*)&g[k + q * 8];
        float4 gv1 = *(const float4*)&g[k + q * 8 + 4];
        float4 bv0 = *(const float4*)&be[k + q * 8];
        float4 bv1 = *(const float4*)&be[k + q * 8 + 4];
        bf16x8 af[4], bfr[4];
        #pragma unroll
        for (int i = 0; i < 4; ++i) {
            const float* pA = Ab + (size_t)i * 16 * 512 + k;
            float4 x0 = *(const float4*)pA;
            float4 x1 = *(const float4*)(pA + 4);
            float4 t0, t1;
            t0.x = fmaf((x0.x - mu[i]) * rstd[i], gv0.x, bv0.x);
            t0.y = fmaf((x0.y - mu[i]) * rstd[i], gv0.y, bv0.y);
            t0.z = fmaf((x0.z - mu[i]) * rstd[i], gv0.z, bv0.z);
            t0.w = fmaf((x0.w - mu[i]) * rstd[i], gv0.w, bv0.w);
            t1.x = fmaf((x1.x - mu[i]) * rstd[i], gv1.x, bv1.x);
            t1.y = fmaf((x1.y - mu[i]) * rstd[i], gv1.y, bv1.y);
            t1.z = fmaf((x1.z - mu[i]) * rstd[i], gv1.z, bv1.z);
            t1.w = fmaf((x1.w - mu[i]) * rstd[i], gv1.w, bv1.w);
            af[i]  = cvt8(t0, t1);
            bfr[i] = *(const bf16x8*)(Bb + (size_t)i * 16 * 512 + k);
        }
        #pragma unroll
        for (int mi = 0; mi < 4; ++mi)
            #pragma unroll
            for (int ni = 0; ni < 4; ++ni)
                acc[mi][ni] = __builtin_amdgcn_mfma_f32_16x16x32_bf16(
                    af[mi], bfr[ni], acc[mi][ni], 0, 0, 0);
    }

    #pragma unroll
    for (int mi = 0; mi < 4; ++mi)
        #pragma unroll
        for (int ni = 0; ni < 4; ++ni)
            #pragma unroll
            for (int r = 0; r < 4; ++r)
                red[wave][mi * 16 + q * 4 + r][ni * 16 + mj] = acc[mi][ni][r];
    __syncthreads();

    #pragma unroll
    for (int g4 = 0; g4 < 4; ++g4) {
        const int idx = g4 * 1024 + tid * 4;
        const int row = idx >> 6, col = idx & 63;
        float4 v0 = *(float4*)&red[0][row][col];
        float4 v1 = *(float4*)&red[1][row][col];
        float4 v2 = *(float4*)&red[2][row][col];
        float4 v3 = *(float4*)&red[3][row][col];
        float4 o;
        o.x = (v0.x + v1.x) + (v2.x + v3.x);
        o.y = (v0.y + v1.y) + (v2.y + v3.y);
        o.z = (v0.z + v1.z) + (v2.z + v3.z);
        o.w = (v0.w + v1.w) + (v2.w + v3.w);
        if (bias) {
            float4 bv = *(const float4*)&bias[bcol + col];
            o.x += bv.x; o.y += bv.y; o.z += bv.z; o.w += bv.w;
        }
        *(float4*)&C[(size_t)(brow + row) * 512 + bcol + col] = o;
    }
}

// ---------------------------------------------------------------------------
// Fused scores + aggregation. 512 blocks: block u -> (b = u>>4, e0 = (u&15)*4)
// computes 4x36 scores (hi rows reused across 4 e's). The 16th finishing
// block of each batch b then does the softmax + LN-folded aggregation,
// reading raw relu'd ia (LN folded via stats).
// ---------------------------------------------------------------------------
__global__ __launch_bounds__(256) void scores_agg_kernel(
    const float* __restrict__ ht, const float* __restrict__ hi,
    const float* __restrict__ ia_raw,
    const float* __restrict__ W2, const float* __restrict__ b2,
    const float* __restrict__ stats2,     // image stats (row b*36+r)
    const float* __restrict__ g, const float* __restrict__ beta,
    float* __restrict__ out_scores, float* __restrict__ out_agg,
    int* __restrict__ counters)
{
    const int u    = blockIdx.x;
    const int b    = u >> 4;
    const int e0   = (u & 15) * 4;
    const int tid  = threadIdx.x;
    const int lane = tid & 63;
    const int wave = tid >> 6;

    // ---- scores for (b, e0..e0+3) ----
    float htv[4][8], w2v[8];
    #pragma unroll
    for (int e = 0; e < 4; ++e) {
        const float* htp = ht + (size_t)(b * 64 + e0 + e) * 512;
        #pragma unroll
        for (int j = 0; j < 8; ++j) htv[e][j] = htp[lane + 64 * j];
    }
    #pragma unroll
    for (int j = 0; j < 8; ++j) w2v[j] = W2[lane + 64 * j];
    const float bb = b2[0];
    const float* hib = hi + (size_t)b * 36 * 512;

    for (int r = wave; r < 36; r += 4) {
        const float* hir = hib + (size_t)r * 512;
        float hv[8];
        #pragma unroll
        for (int j = 0; j < 8; ++j) hv[j] = hir[lane + 64 * j];
        float a0 = 0.f, a1 = 0.f, a2 = 0.f, a3 = 0.f;
        #pragma unroll
        for (int j = 0; j < 8; ++j) {
            a0 = fmaf(fmaxf(htv[0][j] + hv[j], 0.f), w2v[j], a0);
            a1 = fmaf(fmaxf(htv[1][j] + hv[j], 0.f), w2v[j], a1);
            a2 = fmaf(fmaxf(htv[2][j] + hv[j], 0.f), w2v[j], a2);
            a3 = fmaf(fmaxf(htv[3][j] + hv[j], 0.f), w2v[j], a3);
        }
        #pragma unroll
        for (int off = 32; off; off >>= 1) {
            a0 += __shfl_down(a0, off);
            a1 += __shfl_down(a1, off);
            a2 += __shfl_down(a2, off);
            a3 += __shfl_down(a3, off);
        }
        if (lane == 0) {
            float* sp = out_scores + (size_t)(b * 64 + e0) * 36 + r;
            sp[0]   = 1.f / (1.f + expf(-(a0 + bb)));
            sp[36]  = 1.f / (1.f + expf(-(a1 + bb)));
            sp[72]  = 1.f / (1.f + expf(-(a2 + bb)));
            sp[108] = 1.f / (1.f + expf(-(a3 + bb)));
        }
    }

    // ---- last-block-of-batch election ----
    __threadfence();                 // make scores visible device-wide
    __shared__ int is_last;
    if (tid == 0) is_last = (atomicAdd(&counters[b], 1) == 15);
    __syncthreads();
    if (!is_last) return;
    __threadfence();                 // acquire other blocks' scores

    // ---- softmax + LN-folded aggregation for batch b ----
    __shared__ float part[4][36];
    __shared__ float wsr[36];
    __shared__ float tmp[36];
    __shared__ float msc[2];
    const float* sc = out_scores + (size_t)b * 2304;

    const int e4 = tid >> 6;
    const int r  = tid & 63;
    if (r < 36) {
        float p = 0.f;
        #pragma unroll
        for (int e = 0; e < 16; ++e) p += expf(sc[(e * 4 + e4) * 36 + r]);
        part[e4][r] = p;
    }
    __syncthreads();
    if (tid < 36) wsr[tid] = part[0][tid] + part[1][tid] + part[2][tid] + part[3][tid];
    __syncthreads();
    if (tid < 64) {
        float v = (tid < 36) ? wsr[tid] : 0.f;
        #pragma unroll
        for (int off = 32; off; off >>= 1) v += __shfl_down(v, off);
        if (tid == 0) msc[0] = 1.f / (v * 64.f);
    }
    __syncthreads();
    if (tid < 36) {
        const int row = b * 36 + tid;
        float2 st = *(const float2*)&stats2[(size_t)row * 2];
        float m   = st.x * (1.f / 512.f);
        float var = st.y * (1.f / 512.f) - m * m;
        float rs  = rsqrtf(var + LN_EPS);
        float W   = wsr[tid] * msc[0];
        wsr[tid]  = W * rs;
        tmp[tid]  = W * rs * m;
    }
    __syncthreads();
    if (tid < 64) {
        float v = (tid < 36) ? tmp[tid] : 0.f;
        #pragma unroll
        for (int off = 32; off; off >>= 1) v += __shfl_down(v, off);
        if (tid == 0) msc[1] = v;
    }
    __syncthreads();
    const float c1 = msc[1];
    const float* ib = ia_raw + (size_t)b * 36 * 512;
    for (int d = tid; d < 512; d += 256) {
        float acc = 0.f;
        #pragma unroll
        for (int rr = 0; rr < 36; ++rr)
            acc = fmaf(wsr[rr], ib[rr * 512 + d], acc);
        out_agg[(size_t)b * 512 + d] = g[d] * (acc - c1) + beta[d] * (1.f / 64.f);
    }
}

// ---------------------------------------------------------------------------
extern "C" void kernel_launch(void* const* d_in, const int* in_sizes, int n_in,
                              void* d_out, int out_size, void* d_ws, size_t ws_size,
                              hipStream_t stream)
{
    const float* text      = (const float*)d_in[0];
    const float* image     = (const float*)d_in[1];
    const float* W_text    = (const float*)d_in[2];
    const float* b_text    = (const float*)d_in[3];
    const float* g_text    = (const float*)d_in[4];
    const float* beta_text = (const float*)d_in[5];
    const float* W_img     = (const float*)d_in[6];
    const float* b_img     = (const float*)d_in[7];
    const float* g_img     = (const float*)d_in[8];
    const float* beta_img  = (const float*)d_in[9];
    const float* W1        = (const float*)d_in[10];
    const float* b1        = (const float*)d_in[11];
    const float* W2        = (const float*)d_in[12];
    const float* b2        = (const float*)d_in[13];

    float* out_scores = (float*)d_out;            // 32*64*36
    float* out_agg    = (float*)d_out + 73728;    // 32*512

    char* ws = (char*)d_ws;
    ushort_t* text_bf  = (ushort_t*)(ws);                 // 3 MB
    ushort_t* image_bf = (ushort_t*)(ws + 3145728);       // 4.5 MB
    float*    ta       = (float*)(ws + 7864320);          // 4 MB (raw relu'd)
    float*    ia       = (float*)(ws + 12058624);         // 2.25 MB (raw relu'd)
    float*    ht       = (float*)(ws + 14417920);         // 4 MB
    float*    hi       = (float*)(ws + 18612224);         // 2.25 MB
    ushort_t* Wt_t     = (ushort_t*)(ws + 20971520);      // 0.75 MB
    ushort_t* Wi_t     = (ushort_t*)(ws + 21757952);      // 2 MB
    ushort_t* W1t_t    = (ushort_t*)(ws + 23855104);      // 0.5 MB
    ushort_t* W1i_t    = (ushort_t*)(ws + 24379392);      // 0.5 MB
    float*    stats    = (float*)(ws + 24903680);         // 3200 x {sum,sumsq}
    int*      counters = (int*)(ws + 24929280);           // 32 ints

    // 1) convert activations + transpose weights + zero stats/counters
    prep_kernel<<<5761, 256, 0, stream>>>(text, image, text_bf, image_bf,
                                          W_text, W_img, W1,
                                          Wt_t, Wi_t, W1t_t, W1i_t,
                                          stats, counters);
    // 2) both projections + bias + relu + row stats
    proj_kernel<<<dim3(8, 50), 256, 0, stream>>>(
        text_bf, Wt_t, b_text, ta, 768,
        image_bf, Wi_t, b_img, ia, 2048,
        stats, 32);
    // 3) h_t / h_i with LN fused on A-load
    h_kernel<<<dim3(8, 50), 256, 0, stream>>>(
        ta, W1t_t, nullptr, ht, g_text, beta_text, 0,
        ia, W1i_t, b1, hi, g_img, beta_img, 2048,
        stats, 32);
    // 4) scores + sigmoid -> out[0]; per-batch tail block does softmax+agg
    scores_agg_kernel<<<512, 256, 0, stream>>>(
        ht, hi, ia, W2, b2, stats + 4096, g_img, beta_img,
        out_scores, out_agg, counters);
}

// Round 7
// 150.688 us; speedup vs baseline: 2.9003x; 1.2659x over previous
//
#include <hip/hip_runtime.h>
#include <math.h>

#define LN_EPS 1e-5f

typedef __attribute__((ext_vector_type(8))) short bf16x8;
typedef __attribute__((ext_vector_type(4))) float f32x4;
typedef unsigned short ushort_t;
typedef unsigned int uint_t;

__device__ __forceinline__ ushort_t f2bf(float f) {
    uint_t u = __float_as_uint(f);
    u += 0x7FFF + ((u >> 16) & 1);          // RNE
    return (ushort_t)(u >> 16);
}

__device__ __forceinline__ bf16x8 cvt8(float4 a, float4 b) {
    bf16x8 r;
    r[0] = (short)f2bf(a.x); r[1] = (short)f2bf(a.y);
    r[2] = (short)f2bf(a.z); r[3] = (short)f2bf(a.w);
    r[4] = (short)f2bf(b.x); r[5] = (short)f2bf(b.y);
    r[6] = (short)f2bf(b.z); r[7] = (short)f2bf(b.w);
    return r;
}

// ---------------------------------------------------------------------------
// Prep: [0,3840) convert activations fp32->bf16; [3840,5760) transpose-convert
// weights [K][512]f32 -> [512][K]bf16; block 5760 zeroes the LN stats.
// ---------------------------------------------------------------------------
__global__ __launch_bounds__(256) void prep_kernel(
    const float* __restrict__ text, const float* __restrict__ image,
    ushort_t* __restrict__ text_bf, ushort_t* __restrict__ image_bf,
    const float* __restrict__ W_text, const float* __restrict__ W_img,
    const float* __restrict__ W1,
    ushort_t* __restrict__ Wt_t, ushort_t* __restrict__ Wi_t,
    ushort_t* __restrict__ W1t_t, ushort_t* __restrict__ W1i_t,
    float* __restrict__ stats)
{
    __shared__ float t[32][33];
    const int bid = blockIdx.x;
    if (bid < 3840) {
        const int i4 = (bid * 256 + threadIdx.x) * 4;
        const float* src; ushort_t* dst; int off;
        if (i4 < 1572864) { src = text;  dst = text_bf;  off = i4; }
        else              { src = image; dst = image_bf; off = i4 - 1572864; }
        float4 v = *(const float4*)(src + off);
        ushort4 o;
        o.x = f2bf(v.x); o.y = f2bf(v.y); o.z = f2bf(v.z); o.w = f2bf(v.w);
        *(ushort4*)(dst + off) = o;
        return;
    }
    if (bid >= 5760) {
        for (int i = threadIdx.x; i < 6400; i += 256) stats[i] = 0.f;
        return;
    }
    int local = bid - 3840;
    const float* src; ushort_t* dst; int K;
    if      (local < 384)  { src = W_text;         dst = Wt_t;  K = 768;  }
    else if (local < 1408) { src = W_img;          dst = Wi_t;  K = 2048; local -= 384; }
    else if (local < 1664) { src = W1;             dst = W1t_t; K = 512;  local -= 1408; }
    else                   { src = W1 + 512 * 512; dst = W1i_t; K = 512;  local -= 1664; }
    const int ntk = K / 32;
    const int k0 = (local % ntk) * 32;
    const int n0 = (local / ntk) * 32;
    const int x = threadIdx.x % 32, y = threadIdx.x / 32;
    #pragma unroll
    for (int j = 0; j < 4; ++j)
        t[y + 8 * j][x] = src[(size_t)(k0 + y + 8 * j) * 512 + n0 + x];
    __syncthreads();
    #pragma unroll
    for (int j = 0; j < 4; ++j)
        dst[(size_t)(n0 + y + 8 * j) * K + k0 + x] = f2bf(t[x][y + 8 * j]);
}

// ---------------------------------------------------------------------------
// Projection GEMM (bf16 A + bf16 Bt, both K-contiguous): barrier-free
// split-K over 4 waves, 64x64 tile, relu+bias epilogue + per-row LN stats.
// Two problems per launch (y < ysplit -> text).
// ---------------------------------------------------------------------------
__global__ __launch_bounds__(256) void proj_kernel(
    const ushort_t* __restrict__ A0, const ushort_t* __restrict__ B0,
    const float* __restrict__ bias0, float* __restrict__ C0, int K0,
    const ushort_t* __restrict__ A1, const ushort_t* __restrict__ B1,
    const float* __restrict__ bias1, float* __restrict__ C1, int K1,
    float* __restrict__ stats, int ysplit)
{
    __shared__ __align__(16) float red[4][64][64];    // 64 KB

    const ushort_t* A; const ushort_t* Bt; const float* bias; float* C; int K, srow;
    int yy = blockIdx.y;
    if (yy < ysplit) { A = A0; Bt = B0; bias = bias0; C = C0; K = K0; srow = yy * 64; }
    else { A = A1; Bt = B1; bias = bias1; C = C1; K = K1; yy -= ysplit; srow = 2048 + yy * 64; }

    const int tid  = threadIdx.x;
    const int wave = tid >> 6;
    const int lane = tid & 63;
    const int q    = lane >> 4;
    const int mj   = lane & 15;
    const int brow = yy * 64;
    const int bcol = blockIdx.x * 64;

    const ushort_t* Ab = A  + (size_t)(brow + mj) * K + q * 8;
    const ushort_t* Bb = Bt + (size_t)(bcol + mj) * K + q * 8;
    const int kw0    = wave * (K >> 2);
    const int ksteps = K >> 7;

    f32x4 acc[4][4] = {};

    #pragma unroll 2
    for (int s = 0; s < ksteps; ++s) {
        const int k = kw0 + s * 32;
        bf16x8 af[4], bfr[4];
        #pragma unroll
        for (int i = 0; i < 4; ++i) {
            af[i]  = *(const bf16x8*)(Ab + (size_t)i * 16 * K + k);
            bfr[i] = *(const bf16x8*)(Bb + (size_t)i * 16 * K + k);
        }
        #pragma unroll
        for (int mi = 0; mi < 4; ++mi)
            #pragma unroll
            for (int ni = 0; ni < 4; ++ni)
                acc[mi][ni] = __builtin_amdgcn_mfma_f32_16x16x32_bf16(
                    af[mi], bfr[ni], acc[mi][ni], 0, 0, 0);
    }

    #pragma unroll
    for (int mi = 0; mi < 4; ++mi)
        #pragma unroll
        for (int ni = 0; ni < 4; ++ni)
            #pragma unroll
            for (int r = 0; r < 4; ++r)
                red[wave][mi * 16 + q * 4 + r][ni * 16 + mj] = acc[mi][ni][r];
    __syncthreads();

    #pragma unroll
    for (int g4 = 0; g4 < 4; ++g4) {
        const int idx = g4 * 1024 + tid * 4;
        const int row = idx >> 6, col = idx & 63;
        float4 v0 = *(float4*)&red[0][row][col];
        float4 v1 = *(float4*)&red[1][row][col];
        float4 v2 = *(float4*)&red[2][row][col];
        float4 v3 = *(float4*)&red[3][row][col];
        float4 bv = *(const float4*)&bias[bcol + col];
        float4 o;
        o.x = fmaxf((v0.x + v1.x) + (v2.x + v3.x) + bv.x, 0.f);
        o.y = fmaxf((v0.y + v1.y) + (v2.y + v3.y) + bv.y, 0.f);
        o.z = fmaxf((v0.z + v1.z) + (v2.z + v3.z) + bv.z, 0.f);
        o.w = fmaxf((v0.w + v1.w) + (v2.w + v3.w) + bv.w, 0.f);
        *(float4*)&C[(size_t)(brow + row) * 512 + bcol + col] = o;
        float s  = (o.x + o.y) + (o.z + o.w);
        float ss = (o.x * o.x + o.y * o.y) + (o.z * o.z + o.w * o.w);
        #pragma unroll
        for (int m = 1; m < 16; m <<= 1) {
            s  += __shfl_xor(s, m);
            ss += __shfl_xor(ss, m);
        }
        if ((tid & 15) == 0) {
            atomicAdd(&stats[(size_t)(srow + row) * 2], s);
            atomicAdd(&stats[(size_t)(srow + row) * 2 + 1], ss);
        }
    }
}

// ---------------------------------------------------------------------------
// h GEMM with LayerNorm fused on the A-load (fp32 A + stats -> bf16 frags).
// ---------------------------------------------------------------------------
__global__ __launch_bounds__(256) void h_kernel(
    const float* __restrict__ A0, const ushort_t* __restrict__ B0,
    const float* __restrict__ bias0, float* __restrict__ C0,
    const float* __restrict__ g0, const float* __restrict__ be0, int soff0,
    const float* __restrict__ A1, const ushort_t* __restrict__ B1,
    const float* __restrict__ bias1, float* __restrict__ C1,
    const float* __restrict__ g1, const float* __restrict__ be1, int soff1,
    const float* __restrict__ stats, int ysplit)
{
    __shared__ __align__(16) float red[4][64][64];

    const float* A; const ushort_t* Bt; const float* bias; float* C;
    const float* g; const float* be; int soff;
    int yy = blockIdx.y;
    if (yy < ysplit) { A = A0; Bt = B0; bias = bias0; C = C0; g = g0; be = be0; soff = soff0; }
    else { A = A1; Bt = B1; bias = bias1; C = C1; g = g1; be = be1; soff = soff1; yy -= ysplit; }

    const int tid  = threadIdx.x;
    const int wave = tid >> 6;
    const int lane = tid & 63;
    const int q    = lane >> 4;
    const int mj   = lane & 15;
    const int brow = yy * 64;
    const int bcol = blockIdx.x * 64;

    float mu[4], rstd[4];
    #pragma unroll
    for (int i = 0; i < 4; ++i) {
        const int row = soff + brow + i * 16 + mj;
        float2 st = *(const float2*)&stats[(size_t)row * 2];
        float m   = st.x * (1.f / 512.f);
        float var = st.y * (1.f / 512.f) - m * m;
        mu[i] = m; rstd[i] = rsqrtf(var + LN_EPS);
    }

    const float*    Ab = A  + (size_t)(brow + mj) * 512 + q * 8;
    const ushort_t* Bb = Bt + (size_t)(bcol + mj) * 512 + q * 8;
    const int kw0 = wave * 128;

    f32x4 acc[4][4] = {};

    #pragma unroll 2
    for (int s = 0; s < 4; ++s) {
        const int k = kw0 + s * 32;
        float4 gv0 = *(const float4*)&g[k + q * 8];
        float4 gv1 = *(const float4*)&g[k + q * 8 + 4];
        float4 bv0 = *(const float4*)&be[k + q * 8];
        float4 bv1 = *(const float4*)&be[k + q * 8 + 4];
        bf16x8 af[4], bfr[4];
        #pragma unroll
        for (int i = 0; i < 4; ++i) {
            const float* pA = Ab + (size_t)i * 16 * 512 + k;
            float4 x0 = *(const float4*)pA;
            float4 x1 = *(const float4*)(pA + 4);
            float4 t0, t1;
            t0.x = fmaf((x0.x - mu[i]) * rstd[i], gv0.x, bv0.x);
            t0.y = fmaf((x0.y - mu[i]) * rstd[i], gv0.y, bv0.y);
            t0.z = fmaf((x0.z - mu[i]) * rstd[i], gv0.z, bv0.z);
            t0.w = fmaf((x0.w - mu[i]) * rstd[i], gv0.w, bv0.w);
            t1.x = fmaf((x1.x - mu[i]) * rstd[i], gv1.x, bv1.x);
            t1.y = fmaf((x1.y - mu[i]) * rstd[i], gv1.y, bv1.y);
            t1.z = fmaf((x1.z - mu[i]) * rstd[i], gv1.z, bv1.z);
            t1.w = fmaf((x1.w - mu[i]) * rstd[i], gv1.w, bv1.w);
            af[i]  = cvt8(t0, t1);
            bfr[i] = *(const bf16x8*)(Bb + (size_t)i * 16 * 512 + k);
        }
        #pragma unroll
        for (int mi = 0; mi < 4; ++mi)
            #pragma unroll
            for (int ni = 0; ni < 4; ++ni)
                acc[mi][ni] = __builtin_amdgcn_mfma_f32_16x16x32_bf16(
                    af[mi], bfr[ni], acc[mi][ni], 0, 0, 0);
    }

    #pragma unroll
    for (int mi = 0; mi < 4; ++mi)
        #pragma unroll
        for (int ni = 0; ni < 4; ++ni)
            #pragma unroll
            for (int r = 0; r < 4; ++r)
                red[wave][mi * 16 + q * 4 + r][ni * 16 + mj] = acc[mi][ni][r];
    __syncthreads();

    #pragma unroll
    for (int g4 = 0; g4 < 4; ++g4) {
        const int idx = g4 * 1024 + tid * 4;
        const int row = idx >> 6, col = idx & 63;
        float4 v0 = *(float4*)&red[0][row][col];
        float4 v1 = *(float4*)&red[1][row][col];
        float4 v2 = *(float4*)&red[2][row][col];
        float4 v3 = *(float4*)&red[3][row][col];
        float4 o;
        o.x = (v0.x + v1.x) + (v2.x + v3.x);
        o.y = (v0.y + v1.y) + (v2.y + v3.y);
        o.z = (v0.z + v1.z) + (v2.z + v3.z);
        o.w = (v0.w + v1.w) + (v2.w + v3.w);
        if (bias) {
            float4 bv = *(const float4*)&bias[bcol + col];
            o.x += bv.x; o.y += bv.y; o.z += bv.z; o.w += bv.w;
        }
        *(float4*)&C[(size_t)(brow + row) * 512 + bcol + col] = o;
    }
}

// ---------------------------------------------------------------------------
// scores[b,e,r] = sigmoid( sum_d relu(h_t[b,e,d] + h_i[b,r,d]) * W2[d] + b2 )
// One block per (b, 4-e group): 512 blocks; hi rows reused across 4 e's.
// No fences, no atomics.
// ---------------------------------------------------------------------------
__global__ __launch_bounds__(256) void scores_kernel(
    const float* __restrict__ ht, const float* __restrict__ hi,
    const float* __restrict__ W2, const float* __restrict__ b2,
    float* __restrict__ scores)
{
    const int blk  = blockIdx.x;
    const int b    = blk >> 4;
    const int e0   = (blk & 15) * 4;
    const int tid  = threadIdx.x;
    const int lane = tid & 63;
    const int wave = tid >> 6;

    float htv[4][8], w2v[8];
    #pragma unroll
    for (int e = 0; e < 4; ++e) {
        const float* htp = ht + (size_t)(b * 64 + e0 + e) * 512;
        #pragma unroll
        for (int j = 0; j < 8; ++j) htv[e][j] = htp[lane + 64 * j];
    }
    #pragma unroll
    for (int j = 0; j < 8; ++j) w2v[j] = W2[lane + 64 * j];
    const float bb = b2[0];
    const float* hib = hi + (size_t)b * 36 * 512;

    for (int r = wave; r < 36; r += 4) {
        const float* hir = hib + (size_t)r * 512;
        float hv[8];
        #pragma unroll
        for (int j = 0; j < 8; ++j) hv[j] = hir[lane + 64 * j];
        float a0 = 0.f, a1 = 0.f, a2 = 0.f, a3 = 0.f;
        #pragma unroll
        for (int j = 0; j < 8; ++j) {
            a0 = fmaf(fmaxf(htv[0][j] + hv[j], 0.f), w2v[j], a0);
            a1 = fmaf(fmaxf(htv[1][j] + hv[j], 0.f), w2v[j], a1);
            a2 = fmaf(fmaxf(htv[2][j] + hv[j], 0.f), w2v[j], a2);
            a3 = fmaf(fmaxf(htv[3][j] + hv[j], 0.f), w2v[j], a3);
        }
        #pragma unroll
        for (int off = 32; off; off >>= 1) {
            a0 += __shfl_down(a0, off);
            a1 += __shfl_down(a1, off);
            a2 += __shfl_down(a2, off);
            a3 += __shfl_down(a3, off);
        }
        if (lane == 0) {
            float* sp = scores + (size_t)(b * 64 + e0) * 36 + r;
            sp[0]   = 1.f / (1.f + expf(-(a0 + bb)));
            sp[36]  = 1.f / (1.f + expf(-(a1 + bb)));
            sp[72]  = 1.f / (1.f + expf(-(a2 + bb)));
            sp[108] = 1.f / (1.f + expf(-(a3 + bb)));
        }
    }
}

// ---------------------------------------------------------------------------
// Per-batch softmax + aggregation with LN folded algebraically:
//   out_d = g_d * (sum_r W'_r * x_rd - c1) + beta_d / 64
// W'_r = softmaxweight_r * rstd_r, c1 = sum_r W'_r * mu_r, x = raw relu'd ia.
// ---------------------------------------------------------------------------
__global__ __launch_bounds__(256) void agg_kernel(
    const float* __restrict__ scores, const float* __restrict__ ia_raw,
    const float* __restrict__ stats2,   // image stats base (row b*36+r)
    const float* __restrict__ g, const float* __restrict__ beta,
    float* __restrict__ outAgg)
{
    const int b   = blockIdx.x;
    const int tid = threadIdx.x;
    const float* sc = scores + (size_t)b * 2304;

    __shared__ float part[4][36];
    __shared__ float wsr[36];
    __shared__ float tmp[36];
    __shared__ float msc[2];

    const int e4 = tid >> 6;
    const int r  = tid & 63;
    if (r < 36) {
        float p = 0.f;
        #pragma unroll
        for (int e = 0; e < 16; ++e) p += expf(sc[(e * 4 + e4) * 36 + r]);
        part[e4][r] = p;
    }
    __syncthreads();
    if (tid < 36) wsr[tid] = part[0][tid] + part[1][tid] + part[2][tid] + part[3][tid];
    __syncthreads();
    if (tid < 64) {
        float v = (tid < 36) ? wsr[tid] : 0.f;
        #pragma unroll
        for (int off = 32; off; off >>= 1) v += __shfl_down(v, off);
        if (tid == 0) msc[0] = 1.f / (v * 64.f);
    }
    __syncthreads();
    if (tid < 36) {
        const int row = b * 36 + tid;
        float2 st = *(const float2*)&stats2[(size_t)row * 2];
        float m   = st.x * (1.f / 512.f);
        float var = st.y * (1.f / 512.f) - m * m;
        float rs  = rsqrtf(var + LN_EPS);
        float W   = wsr[tid] * msc[0];
        wsr[tid]  = W * rs;
        tmp[tid]  = W * rs * m;
    }
    __syncthreads();
    if (tid < 64) {
        float v = (tid < 36) ? tmp[tid] : 0.f;
        #pragma unroll
        for (int off = 32; off; off >>= 1) v += __shfl_down(v, off);
        if (tid == 0) msc[1] = v;
    }
    __syncthreads();
    const float c1 = msc[1];
    const float* ib = ia_raw + (size_t)b * 36 * 512;
    for (int d = tid; d < 512; d += 256) {
        float acc = 0.f;
        #pragma unroll
        for (int rr = 0; rr < 36; ++rr)
            acc = fmaf(wsr[rr], ib[rr * 512 + d], acc);
        outAgg[(size_t)b * 512 + d] = g[d] * (acc - c1) + beta[d] * (1.f / 64.f);
    }
}

// ---------------------------------------------------------------------------
extern "C" void kernel_launch(void* const* d_in, const int* in_sizes, int n_in,
                              void* d_out, int out_size, void* d_ws, size_t ws_size,
                              hipStream_t stream)
{
    const float* text      = (const float*)d_in[0];
    const float* image     = (const float*)d_in[1];
    const float* W_text    = (const float*)d_in[2];
    const float* b_text    = (const float*)d_in[3];
    const float* g_text    = (const float*)d_in[4];
    const float* beta_text = (const float*)d_in[5];
    const float* W_img     = (const float*)d_in[6];
    const float* b_img     = (const float*)d_in[7];
    const float* g_img     = (const float*)d_in[8];
    const float* beta_img  = (const float*)d_in[9];
    const float* W1        = (const float*)d_in[10];
    const float* b1        = (const float*)d_in[11];
    const float* W2        = (const float*)d_in[12];
    const float* b2        = (const float*)d_in[13];

    float* out_scores = (float*)d_out;            // 32*64*36
    float* out_agg    = (float*)d_out + 73728;    // 32*512

    char* ws = (char*)d_ws;
    ushort_t* text_bf  = (ushort_t*)(ws);                 // 3 MB
    ushort_t* image_bf = (ushort_t*)(ws + 3145728);       // 4.5 MB
    float*    ta       = (float*)(ws + 7864320);          // 4 MB (raw relu'd)
    float*    ia       = (float*)(ws + 12058624);         // 2.25 MB (raw relu'd)
    float*    ht       = (float*)(ws + 14417920);         // 4 MB
    float*    hi       = (float*)(ws + 18612224);         // 2.25 MB
    ushort_t* Wt_t     = (ushort_t*)(ws + 20971520);      // 0.75 MB
    ushort_t* Wi_t     = (ushort_t*)(ws + 21757952);      // 2 MB
    ushort_t* W1t_t    = (ushort_t*)(ws + 23855104);      // 0.5 MB
    ushort_t* W1i_t    = (ushort_t*)(ws + 24379392);      // 0.5 MB
    float*    stats    = (float*)(ws + 24903680);         // 3200 x {sum,sumsq}

    // 1) convert activations + transpose weights + zero stats
    prep_kernel<<<5761, 256, 0, stream>>>(text, image, text_bf, image_bf,
                                          W_text, W_img, W1,
                                          Wt_t, Wi_t, W1t_t, W1i_t, stats);
    // 2) both projections + bias + relu + row stats
    proj_kernel<<<dim3(8, 50), 256, 0, stream>>>(
        text_bf, Wt_t, b_text, ta, 768,
        image_bf, Wi_t, b_img, ia, 2048,
        stats, 32);
    // 3) h_t / h_i with LN fused on A-load
    h_kernel<<<dim3(8, 50), 256, 0, stream>>>(
        ta, W1t_t, nullptr, ht, g_text, beta_text, 0,
        ia, W1i_t, b1, hi, g_img, beta_img, 2048,
        stats, 32);
    // 4) pair scores + sigmoid -> out[0]
    scores_kernel<<<512, 256, 0, stream>>>(ht, hi, W2, b2, out_scores);
    // 5) softmax + aggregation (LN folded) -> out[1]
    agg_kernel<<<32, 256, 0, stream>>>(out_scores, ia, stats + 4096,
                                       g_img, beta_img, out_agg);
}